// Round 1
// baseline (96.020 us; speedup 1.0000x reference)
//
#include <hip/hip_runtime.h>

// Causal depthwise conv1d, dimension-last.
//   x: (B=4, L=4096, D=2048) fp32
//   w: (D=2048, K=4) fp32
//   y[b,t,d] = sum_{j=0}^{3} w[d,j] * x[b, t-3+j, d]   (zero-pad t<0)
//
// Memory-bound: 128 MiB in + 128 MiB out. Strategy: 1 thread = float4 of
// channels for one (b,t). Coalesced float4 loads/stores; the 4x temporal
// reuse of x rows (8 KiB apart) is absorbed by L2.

static constexpr int D_MODEL = 2048;
static constexpr int KSZ     = 4;
static constexpr int D4      = D_MODEL / 4;   // 512 float4 groups per row
static constexpr int L_SEQ   = 4096;

__device__ __forceinline__ float f4_get(const float4& v, int j) {
    // j is compile-time constant under full unroll
    return j == 0 ? v.x : (j == 1 ? v.y : (j == 2 ? v.z : v.w));
}

__global__ __launch_bounds__(256) void ShortConvolution_41575283425757_kernel(
    const float4* __restrict__ x4,
    const float4* __restrict__ w4,
    float4* __restrict__ y4,
    int total4)
{
    const int tid0   = blockIdx.x * blockDim.x + threadIdx.x;
    const int stride = gridDim.x * blockDim.x;   // 524288, multiple of D4

    // Channel group is invariant across the grid-stride loop (stride % D4 == 0)
    const int d4 = tid0 & (D4 - 1);
    // w rows d..d+3 are 16 contiguous floats = 4 float4
    const float4 wr0 = w4[d4 * 4 + 0];
    const float4 wr1 = w4[d4 * 4 + 1];
    const float4 wr2 = w4[d4 * 4 + 2];
    const float4 wr3 = w4[d4 * 4 + 3];

    for (int i = tid0; i < total4; i += stride) {
        const int bt = i / D4;              // flat (b*L + t) row index
        const int t  = bt & (L_SEQ - 1);    // L is power of two

        float4 acc = make_float4(0.f, 0.f, 0.f, 0.f);
        #pragma unroll
        for (int j = 0; j < KSZ; ++j) {
            const int tt = t - (KSZ - 1) + j;
            if (tt >= 0) {
                const float4 xv = x4[i + (j - (KSZ - 1)) * D4];
                acc.x += f4_get(wr0, j) * xv.x;
                acc.y += f4_get(wr1, j) * xv.y;
                acc.z += f4_get(wr2, j) * xv.z;
                acc.w += f4_get(wr3, j) * xv.w;
            }
        }
        y4[i] = acc;
    }
}

extern "C" void kernel_launch(void* const* d_in, const int* in_sizes, int n_in,
                              void* d_out, int out_size, void* d_ws, size_t ws_size,
                              hipStream_t stream) {
    const float4* x4 = (const float4*)d_in[0];
    const float4* w4 = (const float4*)d_in[1];
    float4*       y4 = (float4*)d_out;

    const int total4 = out_size / 4;        // 8,388,608 float4 outputs

    dim3 block(256);
    dim3 grid(2048);                        // grid-stride x16; stride % D4 == 0
    ShortConvolution_41575283425757_kernel<<<grid, block, 0, stream>>>(
        x4, w4, y4, total4);
}

// Round 2
// 51.295 us; speedup vs baseline: 1.8719x; 1.8719x over previous
//
#include <hip/hip_runtime.h>

// Causal depthwise conv1d, dimension-last.
//   x: (B=4, L=4096, D=2048) fp32
//   w: (D=2048, K=4) fp32
//   y[b,t,d] = sum_{j=0}^{3} w[d,j] * x[b, t-3+j, d]   (zero-pad t<0)
//
// Round-1 lesson: FETCH_SIZE was 2x input (cross-XCD L2 thrash on the 4-tap
// reuse). Fix: sliding-window in REGISTERS — each thread walks T=32
// consecutive time steps for its channel group, keeping the last 3 x-rows
// live. Each x element is loaded once (+3-row halo per strip, ~9%).
// Non-temporal loads/stores: pure streaming, skip cache pollution.

typedef float v4 __attribute__((ext_vector_type(4)));

static constexpr int L_SEQ  = 4096;
static constexpr int D4     = 512;          // 2048 channels / 4 per thread
static constexpr int T      = 32;           // time steps per strip
static constexpr int STRIPS = L_SEQ / T;    // 128

__global__ __launch_bounds__(256) void ShortConvolution_41575283425757_kernel(
    const v4* __restrict__ x4,
    const v4* __restrict__ w4,
    v4* __restrict__ y4)
{
    const int tid  = threadIdx.x;
    const int bid  = blockIdx.x;            // B * STRIPS * 2 = 1024 blocks
    const int half = bid & 1;               // which half-row of channels
    const int s    = (bid >> 1) & (STRIPS - 1);
    const int b    = bid >> 8;              // 1 + log2(STRIPS) = 8 bits
    const int d4   = (half << 8) + tid;     // this thread's channel group
    const int t0   = s * T;

    // Weight rows for channels 4*d4 .. 4*d4+3 (each v4 = taps j0..j3),
    // re-shuffled tap-major: ta[k] = w[ch_k][0], etc. -> conv is pure v4 FMA.
    const v4 w0 = w4[d4 * 4 + 0];
    const v4 w1 = w4[d4 * 4 + 1];
    const v4 w2 = w4[d4 * 4 + 2];
    const v4 w3 = w4[d4 * 4 + 3];
    const v4 ta = {w0[0], w1[0], w2[0], w3[0]};
    const v4 tb = {w0[1], w1[1], w2[1], w3[1]};
    const v4 tc = {w0[2], w1[2], w2[2], w3[2]};
    const v4 td = {w0[3], w1[3], w2[3], w3[3]};

    int base = (b * L_SEQ + t0) * D4 + d4;  // v4-unit index of (b, t0, d4)

    // 3-row causal halo (previous strip's tail, or zeros at t=0)
    v4 xm3, xm2, xm1;
    if (t0 == 0) {
        xm3 = (v4)(0.0f); xm2 = (v4)(0.0f); xm1 = (v4)(0.0f);
    } else {
        xm3 = x4[base - 3 * D4];
        xm2 = x4[base - 2 * D4];
        xm1 = x4[base - 1 * D4];
    }

    #pragma unroll
    for (int tt = 0; tt < T; tt += 4) {
        // 4 independent 16B streaming loads in flight
        const v4 c0 = __builtin_nontemporal_load(&x4[base + 0 * D4]);
        const v4 c1 = __builtin_nontemporal_load(&x4[base + 1 * D4]);
        const v4 c2 = __builtin_nontemporal_load(&x4[base + 2 * D4]);
        const v4 c3 = __builtin_nontemporal_load(&x4[base + 3 * D4]);

        const v4 y0 = ta * xm3 + tb * xm2 + tc * xm1 + td * c0;
        const v4 y1 = ta * xm2 + tb * xm1 + tc * c0  + td * c1;
        const v4 y2 = ta * xm1 + tb * c0  + tc * c1  + td * c2;
        const v4 y3 = ta * c0  + tb * c1  + tc * c2  + td * c3;

        __builtin_nontemporal_store(y0, &y4[base + 0 * D4]);
        __builtin_nontemporal_store(y1, &y4[base + 1 * D4]);
        __builtin_nontemporal_store(y2, &y4[base + 2 * D4]);
        __builtin_nontemporal_store(y3, &y4[base + 3 * D4]);

        xm3 = c1; xm2 = c2; xm1 = c3;
        base += 4 * D4;
    }
}

extern "C" void kernel_launch(void* const* d_in, const int* in_sizes, int n_in,
                              void* d_out, int out_size, void* d_ws, size_t ws_size,
                              hipStream_t stream) {
    const v4* x4 = (const v4*)d_in[0];
    const v4* w4 = (const v4*)d_in[1];
    v4*       y4 = (v4*)d_out;

    dim3 block(256);
    dim3 grid(4 /*B*/ * STRIPS * 2);        // 1024 blocks
    ShortConvolution_41575283425757_kernel<<<grid, block, 0, stream>>>(x4, w4, y4);
}

// Round 3
// 46.224 us; speedup vs baseline: 2.0773x; 1.1097x over previous
//
#include <hip/hip_runtime.h>

// Causal depthwise conv1d, dimension-last.
//   x: (B=4, L=4096, D=2048) fp32
//   w: (D=2048, K=4) fp32
//   y[b,t,d] = sum_{j=0}^{3} w[d,j] * x[b, t-3+j, d]   (zero-pad t<0)
//
// Round-2 state: register sliding window, 51.3 us @ ~5.5 TB/s (87% of copy
// ceiling). Round-3 changes:
//   - T=32 -> 64: halo overfetch 9.4% -> 4.7%.
//   - plain (cached) loads instead of nontemporal: nt bypasses L2 on the
//     read path and is the suspect for the BW gap. nt stores kept (pure
//     streaming writes, full-line).
// Occupancy drops to 8 waves/CU; in-flight-bytes model says that's 10x more
// than needed to cover HBM latency.

typedef float v4 __attribute__((ext_vector_type(4)));

static constexpr int L_SEQ  = 4096;
static constexpr int D4     = 512;          // 2048 channels / 4 per thread
static constexpr int T      = 64;           // time steps per strip
static constexpr int STRIPS = L_SEQ / T;    // 64

__global__ __launch_bounds__(256) void ShortConvolution_41575283425757_kernel(
    const v4* __restrict__ x4,
    const v4* __restrict__ w4,
    v4* __restrict__ y4)
{
    const int tid  = threadIdx.x;
    const int bid  = blockIdx.x;            // B * STRIPS * 2 = 512 blocks
    const int half = bid & 1;               // which half-row of channels
    const int s    = (bid >> 1) & (STRIPS - 1);
    const int b    = bid >> 7;              // 1 + log2(STRIPS) = 7 bits
    const int d4   = (half << 8) + tid;     // this thread's channel group
    const int t0   = s * T;

    // Weight rows for channels 4*d4 .. 4*d4+3, re-shuffled tap-major so the
    // convolution is pure v4 FMA.
    const v4 w0 = w4[d4 * 4 + 0];
    const v4 w1 = w4[d4 * 4 + 1];
    const v4 w2 = w4[d4 * 4 + 2];
    const v4 w3 = w4[d4 * 4 + 3];
    const v4 ta = {w0[0], w1[0], w2[0], w3[0]};
    const v4 tb = {w0[1], w1[1], w2[1], w3[1]};
    const v4 tc = {w0[2], w1[2], w2[2], w3[2]};
    const v4 td = {w0[3], w1[3], w2[3], w3[3]};

    int base = (b * L_SEQ + t0) * D4 + d4;  // v4-unit index of (b, t0, d4)

    // 3-row causal halo (previous strip's tail, or zeros at t=0)
    v4 xm3, xm2, xm1;
    if (t0 == 0) {
        xm3 = (v4)(0.0f); xm2 = (v4)(0.0f); xm1 = (v4)(0.0f);
    } else {
        xm3 = x4[base - 3 * D4];
        xm2 = x4[base - 2 * D4];
        xm1 = x4[base - 1 * D4];
    }

    #pragma unroll
    for (int tt = 0; tt < T; tt += 4) {
        // 4 independent 16B loads in flight (cached path)
        const v4 c0 = x4[base + 0 * D4];
        const v4 c1 = x4[base + 1 * D4];
        const v4 c2 = x4[base + 2 * D4];
        const v4 c3 = x4[base + 3 * D4];

        const v4 y0 = ta * xm3 + tb * xm2 + tc * xm1 + td * c0;
        const v4 y1 = ta * xm2 + tb * xm1 + tc * c0  + td * c1;
        const v4 y2 = ta * xm1 + tb * c0  + tc * c1  + td * c2;
        const v4 y3 = ta * c0  + tb * c1  + tc * c2  + td * c3;

        __builtin_nontemporal_store(y0, &y4[base + 0 * D4]);
        __builtin_nontemporal_store(y1, &y4[base + 1 * D4]);
        __builtin_nontemporal_store(y2, &y4[base + 2 * D4]);
        __builtin_nontemporal_store(y3, &y4[base + 3 * D4]);

        xm3 = c1; xm2 = c2; xm1 = c3;
        base += 4 * D4;
    }
}

extern "C" void kernel_launch(void* const* d_in, const int* in_sizes, int n_in,
                              void* d_out, int out_size, void* d_ws, size_t ws_size,
                              hipStream_t stream) {
    const v4* x4 = (const v4*)d_in[0];
    const v4* w4 = (const v4*)d_in[1];
    v4*       y4 = (v4*)d_out;

    dim3 block(256);
    dim3 grid(4 /*B*/ * STRIPS * 2);        // 512 blocks
    ShortConvolution_41575283425757_kernel<<<grid, block, 0, stream>>>(x4, w4, y4);
}

// Round 4
// 44.679 us; speedup vs baseline: 2.1491x; 1.0346x over previous
//
#include <hip/hip_runtime.h>

// Causal depthwise conv1d, dimension-last.
//   x: (B=4, L=4096, D=2048) fp32
//   w: (D=2048, K=4) fp32
//   y[b,t,d] = sum_{j=0}^{3} w[d,j] * x[b, t-3+j, d]   (zero-pad t<0)
//
// Round-3 state: 46.2 us @ ~5.93 TB/s effective (94% of copy ceiling).
// Round-4 change: T=64 -> 128 (halo overfetch 4.7% -> 2.3%). To keep full
// CU coverage with only 32 strips, blocks shrink to one wave (64 threads)
// and channels split into 8 octants: 4*32*8 = 1024 blocks, 4 waves/CU.
// In-flight bytes (4 waves x 64 lanes x 4 x 16B = 16 KB/CU) still covers
// HBM latency (~9.2 KB needed).

typedef float v4 __attribute__((ext_vector_type(4)));

static constexpr int L_SEQ  = 4096;
static constexpr int D4     = 512;          // 2048 channels / 4 per thread
static constexpr int T      = 128;          // time steps per strip
static constexpr int STRIPS = L_SEQ / T;    // 32

__global__ __launch_bounds__(64) void ShortConvolution_41575283425757_kernel(
    const v4* __restrict__ x4,
    const v4* __restrict__ w4,
    v4* __restrict__ y4)
{
    const int lane = threadIdx.x;           // 0..63
    const int bid  = blockIdx.x;            // B * STRIPS * 8 = 1024 blocks
    const int oct  = bid & 7;               // channel octant (64 v4-groups)
    const int s    = (bid >> 3) & (STRIPS - 1);
    const int b    = bid >> 8;              // 3 + log2(STRIPS) = 8 bits
    const int d4   = (oct << 6) + lane;     // this thread's channel group
    const int t0   = s * T;

    // Weight rows for channels 4*d4 .. 4*d4+3, re-shuffled tap-major so the
    // convolution is pure v4 FMA.
    const v4 w0 = w4[d4 * 4 + 0];
    const v4 w1 = w4[d4 * 4 + 1];
    const v4 w2 = w4[d4 * 4 + 2];
    const v4 w3 = w4[d4 * 4 + 3];
    const v4 ta = {w0[0], w1[0], w2[0], w3[0]};
    const v4 tb = {w0[1], w1[1], w2[1], w3[1]};
    const v4 tc = {w0[2], w1[2], w2[2], w3[2]};
    const v4 td = {w0[3], w1[3], w2[3], w3[3]};

    int base = (b * L_SEQ + t0) * D4 + d4;  // v4-unit index of (b, t0, d4)

    // 3-row causal halo (previous strip's tail, or zeros at t=0)
    v4 xm3, xm2, xm1;
    if (t0 == 0) {
        xm3 = (v4)(0.0f); xm2 = (v4)(0.0f); xm1 = (v4)(0.0f);
    } else {
        xm3 = x4[base - 3 * D4];
        xm2 = x4[base - 2 * D4];
        xm1 = x4[base - 1 * D4];
    }

    #pragma unroll 4
    for (int tt = 0; tt < T; tt += 4) {
        // 4 independent 16B loads in flight (cached path)
        const v4 c0 = x4[base + 0 * D4];
        const v4 c1 = x4[base + 1 * D4];
        const v4 c2 = x4[base + 2 * D4];
        const v4 c3 = x4[base + 3 * D4];

        const v4 y0 = ta * xm3 + tb * xm2 + tc * xm1 + td * c0;
        const v4 y1 = ta * xm2 + tb * xm1 + tc * c0  + td * c1;
        const v4 y2 = ta * xm1 + tb * c0  + tc * c1  + td * c2;
        const v4 y3 = ta * c0  + tb * c1  + tc * c2  + td * c3;

        __builtin_nontemporal_store(y0, &y4[base + 0 * D4]);
        __builtin_nontemporal_store(y1, &y4[base + 1 * D4]);
        __builtin_nontemporal_store(y2, &y4[base + 2 * D4]);
        __builtin_nontemporal_store(y3, &y4[base + 3 * D4]);

        xm3 = c1; xm2 = c2; xm1 = c3;
        base += 4 * D4;
    }
}

extern "C" void kernel_launch(void* const* d_in, const int* in_sizes, int n_in,
                              void* d_out, int out_size, void* d_ws, size_t ws_size,
                              hipStream_t stream) {
    const v4* x4 = (const v4*)d_in[0];
    const v4* w4 = (const v4*)d_in[1];
    v4*       y4 = (v4*)d_out;

    dim3 block(64);
    dim3 grid(4 /*B*/ * STRIPS * 8);        // 1024 one-wave blocks
    ShortConvolution_41575283425757_kernel<<<grid, block, 0, stream>>>(x4, w4, y4);
}